// Round 10
// baseline (171.242 us; speedup 1.0000x reference)
//
#include <hip/hip_runtime.h>
#include <stdint.h>

#define NN 16384
#define MM 16384
#define DD 8
#define DV 16
#define WAVES 4
#define MT 2                        // 16-row m-tiles per wave
#define ROWS_WAVE (MT * 16)         // 32
#define ROWS_BLK (WAVES * ROWS_WAVE)// 128
#define JSPLIT 16
#define JCHUNK (MM / JSPLIT)        // 1024
#define J32 (JCHUNK / 32)           // 32 iterations per block

typedef short bf8 __attribute__((ext_vector_type(8)));   // 8 bf16 (4 VGPR)
typedef float f32x4 __attribute__((ext_vector_type(4))); // MFMA C/D
typedef float v2f __attribute__((ext_vector_type(2)));   // packed fp32 (VOP3P)

__device__ __forceinline__ unsigned short f2bf(float f) {
    union { float f; uint32_t u; } c; c.f = f;
    uint32_t u = c.u + 0x7FFF + ((c.u >> 16) & 1);       // RNE
    return (unsigned short)(u >> 16);
}
__device__ __forceinline__ float bf2f(unsigned short h) {
    union { float f; uint32_t u; } c; c.u = ((uint32_t)h) << 16;
    return c.f;
}

// Precompute block-invariant MFMA fragments into d_ws (R5/R9-proven):
//  ytbl[tile16][lane]: B-operand frag for S = Xls·Y^T, hi/lo packed in K
//  btbl[tile32][lane]: B-operand frag for out += K·B (direct K-order)
//  sy[j] = sum_d ls_d*y_jd^2
__global__ __launch_bounds__(64) void prep_frags(const float* __restrict__ ls,
                                                 const float* __restrict__ y,
                                                 const float* __restrict__ b,
                                                 bf8* __restrict__ ytbl,
                                                 bf8* __restrict__ btbl,
                                                 float* __restrict__ sy) {
    const int tile = blockIdx.x;      // 0..1023 (j16 tiles)
    const int lane = threadIdx.x;     // 0..63
    const int n = lane & 15, quad = lane >> 4;

    float lsv[DD];
#pragma unroll
    for (int d = 0; d < DD; ++d) lsv[d] = ls[d];

    const float* yr = y + (size_t)(tile * 16 + n) * DD;
    float syv = 0.f;
    bf8 fr;
#pragma unroll
    for (int d = 0; d < DD; ++d) {
        float yv = yr[d];
        syv = fmaf(lsv[d] * yv, yv, syv);
        unsigned short yh = f2bf(yv);
        unsigned short yl = f2bf(yv - bf2f(yh));
        fr[d] = (short)(quad == 3 ? 0 : (quad == 2 ? yl : yh));
    }
    ytbl[tile * 64 + lane] = fr;
    if (quad == 0) sy[tile * 16 + n] = syv;

    if (tile < MM / 32) {             // j32 tiles for phase B
        bf8 bfr;
#pragma unroll
        for (int s = 0; s < 8; ++s) {
            float bv = b[(size_t)(tile * 32 + quad * 8 + s) * DV + n];
            bfr[s] = (short)f2bf(bv);
        }
        btbl[tile * 64 + lane] = bfr;
    }
}

// R9 structure (proven PASS) with ONE change: the Matern transform uses
// native v2f vector arithmetic (pairs = j-tile0/j-tile1 sharing (mt,s)).
// Plain C vector ops — ISel selects v_pk_{fma,add,mul}_f32 via fp-contract;
// NO inline asm (the R6-R8 asm+MFMA mix failed correctness 3x).
// sqrt/exp stay scalar (transcendental pipe has no packed form).
__global__ __launch_bounds__(256, 8) void matern_mfma(const float* __restrict__ ls,
                                                      const float* __restrict__ x,
                                                      const bf8* __restrict__ ytbl,
                                                      const bf8* __restrict__ btbl,
                                                      const float* __restrict__ sy,
                                                      float* __restrict__ out) {
    const int t = threadIdx.x;
    const int lane = t & 63, wave = t >> 6;
    const int n = lane & 15, quad = lane >> 4;
    const int waverow = blockIdx.x * ROWS_BLK + wave * ROWS_WAVE;

    // [wave][mt][m][40]: 80B rows, 16B-aligned reads; <=2-way conflicts (free)
    __shared__ __attribute__((aligned(16))) unsigned short klds[WAVES][MT][16][40];

    float lsv[DD];
#pragma unroll
    for (int d = 0; d < DD; ++d) lsv[d] = ls[d];

    // A-operand frags: lane holds A[m=lane&15][k=quad*8+s]; quad sel hi,lo,hi,0
    bf8 afrag[MT];
#pragma unroll
    for (int mt = 0; mt < MT; ++mt) {
        const float* xr = x + (size_t)(waverow + mt * 16 + n) * DD;
#pragma unroll
        for (int d = 0; d < DD; ++d) {
            float xls = lsv[d] * xr[d];
            unsigned short xh = f2bf(xls);
            unsigned short xl = f2bf(xls - bf2f(xh));
            afrag[mt][d] = (short)(quad == 3 ? 0 : (quad == 1 ? xl : xh));
        }
    }

    // sx broadcast pairs for the C/D rows this lane owns: row = quad*4 + s
    v2f sxq2[MT][4];
#pragma unroll
    for (int mt = 0; mt < MT; ++mt)
#pragma unroll
        for (int s = 0; s < 4; ++s) {
            const float* xr = x + (size_t)(waverow + mt * 16 + quad * 4 + s) * DD;
            float acc = 0.f;
#pragma unroll
            for (int d = 0; d < DD; ++d) acc = fmaf(lsv[d] * xr[d], xr[d], acc);
            sxq2[mt][s] = (v2f){acc, acc};
        }

    const v2f n2v = {-2.f, -2.f};
    const v2f c1v = {2.23606797749979f, 2.23606797749979f};     // sqrt(5)
    const v2f c2v = {1.2909944487358056f, 1.2909944487358056f}; // sqrt(5/3)
    const v2f c3v = {-3.2259641843312987f, -3.2259641843312987f}; // -sqrt(5)*log2(e)
    const v2f onev = {1.f, 1.f};

    f32x4 acc[MT];
#pragma unroll
    for (int mt = 0; mt < MT; ++mt) acc[mt] = (f32x4){0.f, 0.f, 0.f, 0.f};

    const int tile16base = blockIdx.y * (JCHUNK / 16);
    const int tile32base = blockIdx.y * (JCHUNK / 32);

#pragma unroll 1
    for (int it = 0; it < J32; ++it) {
        const int tl0 = tile16base + it * 2;
        bf8 yA = ytbl[(size_t)tl0 * 64 + lane];
        bf8 yB = ytbl[(size_t)(tl0 + 1) * 64 + lane];
        bf8 bb = btbl[(size_t)(tile32base + it) * 64 + lane];
        float syA = sy[tl0 * 16 + n];
        float syB = sy[(tl0 + 1) * 16 + n];
        v2f syv2 = {syA, syB};

#pragma unroll
        for (int mt = 0; mt < MT; ++mt) {
            f32x4 z = (f32x4){0.f, 0.f, 0.f, 0.f};
            f32x4 s0 = __builtin_amdgcn_mfma_f32_16x16x32_bf16(afrag[mt], yA, z, 0, 0, 0);
            f32x4 s1 = __builtin_amdgcn_mfma_f32_16x16x32_bf16(afrag[mt], yB, z, 0, 0, 0);
#pragma unroll
            for (int s = 0; s < 4; ++s) {
                v2f sp;
                sp.x = s0[s];
                sp.y = s1[s];
                v2f d2v = sxq2[mt][s] + syv2 + sp * n2v;   // contracts to pk_add + pk_fma
                float d20 = fmaxf(d2v.x, 0.f);
                float d21 = fmaxf(d2v.y, 0.f);
                float r0 = __builtin_amdgcn_sqrtf(d20);
                float r1 = __builtin_amdgcn_sqrtf(d21);
                v2f rv = {r0, r1};
                v2f tv = rv * c3v;                         // pk_mul
                float e0 = __builtin_amdgcn_exp2f(tv.x);
                float e1 = __builtin_amdgcn_exp2f(tv.y);
                v2f ev = {e0, e1};
                v2f d2c = {d20, d21};
                v2f poly = c1v * rv + onev;                // pk_fma
                poly = c2v * d2c + poly;                   // pk_fma
                v2f kv = poly * ev;                        // pk_mul
                // round-half-up bf16 (k>0; ties differ from RNE by 1 ulp max)
                klds[wave][mt][quad * 4 + s][n] =
                    (unsigned short)((__float_as_uint(kv.x) + 0x8000u) >> 16);
                klds[wave][mt][quad * 4 + s][n + 16] =
                    (unsigned short)((__float_as_uint(kv.y) + 0x8000u) >> 16);
            }
        }
        // C/D->A layout: lane reads A'[m=lane&15][k=quad*8+s] as one 16B LDS read
#pragma unroll
        for (int mt = 0; mt < MT; ++mt) {
            const bf8* kp = (const bf8*)&klds[wave][mt][n][quad * 8];
            acc[mt] = __builtin_amdgcn_mfma_f32_16x16x32_bf16(*kp, bb, acc[mt], 0, 0, 0);
        }
    }

    // Epilogue: D layout row=quad*4+s, col=n; JSPLIT partial sums via atomics
#pragma unroll
    for (int mt = 0; mt < MT; ++mt)
#pragma unroll
        for (int s = 0; s < 4; ++s) {
            const int row = waverow + mt * 16 + quad * 4 + s;
            atomicAdd(out + (size_t)row * DV + n, acc[mt][s]);
        }
}

extern "C" void kernel_launch(void* const* d_in, const int* in_sizes, int n_in,
                              void* d_out, int out_size, void* d_ws, size_t ws_size,
                              hipStream_t stream) {
    const float* ls = (const float*)d_in[0];
    const float* x  = (const float*)d_in[1];
    const float* y  = (const float*)d_in[2];
    const float* b  = (const float*)d_in[3];
    float* out = (float*)d_out;

    char* ws = (char*)d_ws;
    bf8*   ytbl = (bf8*)ws;                        // 1024*64*16B = 1 MB
    bf8*   btbl = (bf8*)(ws + (1 << 20));          // 512*64*16B  = 512 KB
    float* sy   = (float*)(ws + (1 << 20) + (512 << 10)); // 64 KB

    hipMemsetAsync(d_out, 0, (size_t)out_size * sizeof(float), stream);
    prep_frags<<<MM / 16, 64, 0, stream>>>(ls, y, b, ytbl, btbl, sy);
    matern_mfma<<<dim3(NN / ROWS_BLK, JSPLIT), 256, 0, stream>>>(ls, x, ytbl, btbl, sy, out);
}

// Round 11
// 151.731 us; speedup vs baseline: 1.1286x; 1.1286x over previous
//
#include <hip/hip_runtime.h>
#include <stdint.h>

#define NN 16384
#define MM 16384
#define DD 8
#define DV 16
#define WAVES 4
#define MT 2                        // 16-row m-tiles per wave
#define ROWS_WAVE (MT * 16)         // 32
#define ROWS_BLK (WAVES * ROWS_WAVE)// 128
#define JSPLIT 16
#define JCHUNK (MM / JSPLIT)        // 1024
#define J32 (JCHUNK / 32)           // 32 iterations per block

typedef short bf8 __attribute__((ext_vector_type(8)));   // 8 bf16 (4 VGPR)
typedef float f32x4 __attribute__((ext_vector_type(4))); // MFMA C/D

__device__ __forceinline__ unsigned short f2bf(float f) {
    union { float f; uint32_t u; } c; c.f = f;
    uint32_t u = c.u + 0x7FFF + ((c.u >> 16) & 1);       // RNE
    return (unsigned short)(u >> 16);
}
__device__ __forceinline__ float bf2f(unsigned short h) {
    union { float f; uint32_t u; } c; c.u = ((uint32_t)h) << 16;
    return c.f;
}

#define BF16_ONE ((short)0x3F80)

// Fragments with the d2 affine terms FOLDED INTO THE MFMA K-slots:
//   quads 0..2 of B hold -2*y (hi, hi, lo)  [pairs with A hi, lo, hi]
//   quad 3:  A slots {1, 1, sx_hi, sx_lo, 0...} x B slots {sy_hi, sy_lo, 1, 1, 0...}
// so S = sx + sy - 2*(xls_hi*y_hi + xls_lo*y_hi + xls_hi*y_lo) = d2 directly.
//  ytbl[tile16][lane]: B-operand frag for the d2 MFMA
//  btbl[tile32][lane]: B-operand frag for out += K*B (direct K-order)
__global__ __launch_bounds__(64) void prep_frags(const float* __restrict__ ls,
                                                 const float* __restrict__ y,
                                                 const float* __restrict__ b,
                                                 bf8* __restrict__ ytbl,
                                                 bf8* __restrict__ btbl) {
    const int tile = blockIdx.x;      // 0..1023 (j16 tiles)
    const int lane = threadIdx.x;     // 0..63
    const int n = lane & 15, quad = lane >> 4;

    float lsv[DD];
#pragma unroll
    for (int d = 0; d < DD; ++d) lsv[d] = ls[d];

    const float* yr = y + (size_t)(tile * 16 + n) * DD;
    float syv = 0.f;
    unsigned short yh[DD], yl[DD];
#pragma unroll
    for (int d = 0; d < DD; ++d) {
        float yv = yr[d];
        syv = fmaf(lsv[d] * yv, yv, syv);
        yh[d] = f2bf(yv);
        yl[d] = f2bf(yv - bf2f(yh[d]));
    }

    bf8 fr;
    if (quad < 3) {
#pragma unroll
        for (int d = 0; d < DD; ++d) {
            unsigned short base = (quad == 2) ? yl[d] : yh[d];
            // -2 * bf16 value is exact (sign flip + exponent+1): single rounding
            fr[d] = (short)f2bf(-2.f * bf2f(base));
        }
    } else {
        unsigned short sh = f2bf(syv);
        unsigned short sl = f2bf(syv - bf2f(sh));
        fr[0] = (short)sh;      // k=24: 1 * sy_hi
        fr[1] = (short)sl;      // k=25: 1 * sy_lo
        fr[2] = BF16_ONE;       // k=26: sx_hi * 1
        fr[3] = BF16_ONE;       // k=27: sx_lo * 1
        fr[4] = 0; fr[5] = 0; fr[6] = 0; fr[7] = 0;
    }
    ytbl[tile * 64 + lane] = fr;

    if (tile < MM / 32) {             // j32 tiles for phase B
        bf8 bfr;
#pragma unroll
        for (int s = 0; s < 8; ++s) {
            float bv = b[(size_t)(tile * 32 + quad * 8 + s) * DV + n];
            bfr[s] = (short)f2bf(bv);
        }
        btbl[tile * 64 + lane] = bfr;
    }
}

// R9 structure (proven PASS, 162us) with the d2 fold: the phase-A MFMA now
// emits d2 itself (no sy loads, no sx add, no -2 fma in the transform).
// Transform per value: fmax, sqrt, mul, exp, 2x fma, mul, 2-op bf16 cvt.
// Scalar math (R10's v2f regressed); NO inline asm (R6-R8 failure culprit).
__global__ __launch_bounds__(256, 8) void matern_mfma(const float* __restrict__ ls,
                                                      const float* __restrict__ x,
                                                      const bf8* __restrict__ ytbl,
                                                      const bf8* __restrict__ btbl,
                                                      float* __restrict__ out) {
    const int t = threadIdx.x;
    const int lane = t & 63, wave = t >> 6;
    const int n = lane & 15, quad = lane >> 4;
    const int waverow = blockIdx.x * ROWS_BLK + wave * ROWS_WAVE;

    // [wave][mt][m][40]: 80B rows, 16B-aligned reads; <=2-way conflicts (free)
    __shared__ __attribute__((aligned(16))) unsigned short klds[WAVES][MT][16][40];

    float lsv[DD];
#pragma unroll
    for (int d = 0; d < DD; ++d) lsv[d] = ls[d];

    // A-frags: quad 0/2 -> xls_hi, quad 1 -> xls_lo, quad 3 -> {1,1,sx_hi,sx_lo,0..}
    bf8 afrag[MT];
#pragma unroll
    for (int mt = 0; mt < MT; ++mt) {
        const float* xr = x + (size_t)(waverow + mt * 16 + n) * DD;
        float sx = 0.f;
        unsigned short xh[DD], xl[DD];
#pragma unroll
        for (int d = 0; d < DD; ++d) {
            float xv = xr[d];
            float xlsv = lsv[d] * xv;
            sx = fmaf(xlsv, xv, sx);
            xh[d] = f2bf(xlsv);
            xl[d] = f2bf(xlsv - bf2f(xh[d]));
        }
        bf8 fr;
        if (quad == 3) {
            unsigned short sh = f2bf(sx);
            unsigned short sl = f2bf(sx - bf2f(sh));
            fr[0] = BF16_ONE;   // k=24: 1 * sy_hi
            fr[1] = BF16_ONE;   // k=25: 1 * sy_lo
            fr[2] = (short)sh;  // k=26: sx_hi * 1
            fr[3] = (short)sl;  // k=27: sx_lo * 1
            fr[4] = 0; fr[5] = 0; fr[6] = 0; fr[7] = 0;
        } else {
#pragma unroll
            for (int d = 0; d < DD; ++d)
                fr[d] = (short)((quad == 1) ? xl[d] : xh[d]);
        }
        afrag[mt] = fr;
    }

    const float c1 = 2.23606797749979f;      // sqrt(5)
    const float c2 = 1.2909944487358056f;    // sqrt(5/3)
    const float c3 = -3.2259641843312987f;   // -sqrt(5)*log2(e)

    f32x4 acc[MT];
#pragma unroll
    for (int mt = 0; mt < MT; ++mt) acc[mt] = (f32x4){0.f, 0.f, 0.f, 0.f};

    const int tile16base = blockIdx.y * (JCHUNK / 16);
    const int tile32base = blockIdx.y * (JCHUNK / 32);

#pragma unroll 1
    for (int it = 0; it < J32; ++it) {
        const int tl0 = tile16base + it * 2;
        bf8 yA = ytbl[(size_t)tl0 * 64 + lane];
        bf8 yB = ytbl[(size_t)(tl0 + 1) * 64 + lane];
        bf8 bb = btbl[(size_t)(tile32base + it) * 64 + lane];

#pragma unroll
        for (int mt = 0; mt < MT; ++mt) {
            f32x4 z = (f32x4){0.f, 0.f, 0.f, 0.f};
            f32x4 s0 = __builtin_amdgcn_mfma_f32_16x16x32_bf16(afrag[mt], yA, z, 0, 0, 0);
            f32x4 s1 = __builtin_amdgcn_mfma_f32_16x16x32_bf16(afrag[mt], yB, z, 0, 0, 0);
#pragma unroll
            for (int s = 0; s < 4; ++s) {
                // s0/s1 ARE d2 (the MFMA computed sx+sy-2*dot)
                float d20 = fmaxf(s0[s], 0.f);
                float d21 = fmaxf(s1[s], 0.f);
                float r0 = __builtin_amdgcn_sqrtf(d20);
                float r1 = __builtin_amdgcn_sqrtf(d21);
                float e0 = __builtin_amdgcn_exp2f(c3 * r0);
                float e1 = __builtin_amdgcn_exp2f(c3 * r1);
                float k0 = fmaf(c2, d20, fmaf(c1, r0, 1.f)) * e0;
                float k1 = fmaf(c2, d21, fmaf(c1, r1, 1.f)) * e1;
#if __has_builtin(__builtin_amdgcn_cvt_pk_bf16_f32)
                typedef __bf16 bf2v __attribute__((ext_vector_type(2)));
                bf2v pk = __builtin_amdgcn_cvt_pk_bf16_f32(k0, k1);
                union { bf2v v; unsigned short u[2]; } cv; cv.v = pk;
                klds[wave][mt][quad * 4 + s][n] = cv.u[0];
                klds[wave][mt][quad * 4 + s][n + 16] = cv.u[1];
#else
                // round-half-up bf16 (k>0): R10-proven 2-op path
                klds[wave][mt][quad * 4 + s][n] =
                    (unsigned short)((__float_as_uint(k0) + 0x8000u) >> 16);
                klds[wave][mt][quad * 4 + s][n + 16] =
                    (unsigned short)((__float_as_uint(k1) + 0x8000u) >> 16);
#endif
            }
        }
        // C/D->A layout: lane reads A'[m=lane&15][k=quad*8+s] as one 16B LDS read
#pragma unroll
        for (int mt = 0; mt < MT; ++mt) {
            const bf8* kp = (const bf8*)&klds[wave][mt][n][quad * 8];
            acc[mt] = __builtin_amdgcn_mfma_f32_16x16x32_bf16(*kp, bb, acc[mt], 0, 0, 0);
        }
    }

    // Epilogue: D layout row=quad*4+s, col=n; JSPLIT partial sums via atomics
#pragma unroll
    for (int mt = 0; mt < MT; ++mt)
#pragma unroll
        for (int s = 0; s < 4; ++s) {
            const int row = waverow + mt * 16 + quad * 4 + s;
            atomicAdd(out + (size_t)row * DV + n, acc[mt][s]);
        }
}

extern "C" void kernel_launch(void* const* d_in, const int* in_sizes, int n_in,
                              void* d_out, int out_size, void* d_ws, size_t ws_size,
                              hipStream_t stream) {
    const float* ls = (const float*)d_in[0];
    const float* x  = (const float*)d_in[1];
    const float* y  = (const float*)d_in[2];
    const float* b  = (const float*)d_in[3];
    float* out = (float*)d_out;

    char* ws = (char*)d_ws;
    bf8* ytbl = (bf8*)ws;                        // 1024*64*16B = 1 MB
    bf8* btbl = (bf8*)(ws + (1 << 20));          // 512*64*16B  = 512 KB

    hipMemsetAsync(d_out, 0, (size_t)out_size * sizeof(float), stream);
    prep_frags<<<MM / 16, 64, 0, stream>>>(ls, y, b, ytbl, btbl);
    matern_mfma<<<dim3(NN / ROWS_BLK, JSPLIT), 256, 0, stream>>>(ls, x, ytbl, btbl, out);
}

// Round 12
// 138.118 us; speedup vs baseline: 1.2398x; 1.0986x over previous
//
#include <hip/hip_runtime.h>
#include <stdint.h>

#define NN 16384
#define MM 16384
#define DD 8
#define DV 16
#define WAVES 4
#define MT 2                        // 16-row m-tiles per wave
#define ROWS_WAVE (MT * 16)         // 32
#define ROWS_BLK (WAVES * ROWS_WAVE)// 128
#define JSPLIT 32
#define JCHUNK (MM / JSPLIT)        // 512
#define J32 (JCHUNK / 32)           // 16 iterations per block

typedef short bf8 __attribute__((ext_vector_type(8)));   // 8 bf16 (4 VGPR)
typedef float f32x4 __attribute__((ext_vector_type(4))); // MFMA C/D

__device__ __forceinline__ unsigned short f2bf(float f) {
    union { float f; uint32_t u; } c; c.f = f;
    uint32_t u = c.u + 0x7FFF + ((c.u >> 16) & 1);       // RNE
    return (unsigned short)(u >> 16);
}
__device__ __forceinline__ float bf2f(unsigned short h) {
    union { float f; uint32_t u; } c; c.u = ((uint32_t)h) << 16;
    return c.f;
}

#define BF16_ONE ((short)0x3F80)

// Fragments with the d2 affine terms FOLDED INTO THE MFMA K-slots (R11-proven):
//   quads 0..2 of B hold -2*y (hi, hi, lo)  [pairs with A hi, lo, hi]
//   quad 3:  A slots {1, 1, sx_hi, sx_lo, 0...} x B slots {sy_hi, sy_lo, 1, 1, 0...}
// so the MFMA emits d2 = sx + sy - 2*xls.y directly.
// R12: 256-thread blocks (4 tiles each), float4 y/b loads, and d_out zeroing
// folded in (kills the separate memset dispatch).
__global__ __launch_bounds__(256) void prep_frags(const float* __restrict__ ls,
                                                  const float* __restrict__ y,
                                                  const float* __restrict__ b,
                                                  bf8* __restrict__ ytbl,
                                                  bf8* __restrict__ btbl,
                                                  float4* __restrict__ outz) {
    const int tile = blockIdx.x * 4 + (threadIdx.x >> 6);  // 0..1023 (j16 tiles)
    const int lane = threadIdx.x & 63;
    const int n = lane & 15, quad = lane >> 4;

    // zero d_out: 256 blocks * 256 threads = 65536 float4 = 1 MB
    outz[blockIdx.x * 256 + threadIdx.x] = make_float4(0.f, 0.f, 0.f, 0.f);

    float lsv[DD];
#pragma unroll
    for (int d = 0; d < DD; ++d) lsv[d] = ls[d];

    const float4* yr4 = (const float4*)(y + (size_t)(tile * 16 + n) * DD);
    float4 ya = yr4[0], yb = yr4[1];
    float yv[DD] = {ya.x, ya.y, ya.z, ya.w, yb.x, yb.y, yb.z, yb.w};

    float syv = 0.f;
    unsigned short yh[DD], yl[DD];
#pragma unroll
    for (int d = 0; d < DD; ++d) {
        syv = fmaf(lsv[d] * yv[d], yv[d], syv);
        yh[d] = f2bf(yv[d]);
        yl[d] = f2bf(yv[d] - bf2f(yh[d]));
    }

    bf8 fr;
    if (quad < 3) {
#pragma unroll
        for (int d = 0; d < DD; ++d) {
            unsigned short base = (quad == 2) ? yl[d] : yh[d];
            fr[d] = (short)f2bf(-2.f * bf2f(base));   // exact: sign+exp bump
        }
    } else {
        unsigned short sh = f2bf(syv);
        unsigned short sl = f2bf(syv - bf2f(sh));
        fr[0] = (short)sh;      // k=24: 1 * sy_hi
        fr[1] = (short)sl;      // k=25: 1 * sy_lo
        fr[2] = BF16_ONE;       // k=26: sx_hi * 1
        fr[3] = BF16_ONE;       // k=27: sx_lo * 1
        fr[4] = 0; fr[5] = 0; fr[6] = 0; fr[7] = 0;
    }
    ytbl[tile * 64 + lane] = fr;

    if (tile < MM / 32) {             // j32 tiles for phase B
        bf8 bfr;
        const float4* br4 = (const float4*)(b + (size_t)(tile * 32) * DV);
        // lane needs b[tile*32 + quad*8 + s][n], s=0..7 — scalar gather is fine here
#pragma unroll
        for (int s = 0; s < 8; ++s) {
            float bv = b[(size_t)(tile * 32 + quad * 8 + s) * DV + n];
            bfr[s] = (short)f2bf(bv);
        }
        (void)br4;
        btbl[tile * 64 + lane] = bfr;
    }
}

// R11 structure (proven PASS, 151.7us) + VALU micro-trims:
//  - fmax(d2,0) replaced by free |d2| input modifier on sqrt (d2<0 only from
//    rounding noise near 0; k error < 1e-3)
//  - c3^2 pre-folded: t = sqrt(c3^2*|d2|), e = exp2(-t) (neg modifier free),
//    poly = 1 + ln2*t + c2*|d2|   (c1/|c3| == ln2 exactly)
//  - JSPLIT 16->32: 4096 blocks, 2x oversubscription for tail/packing
__global__ __launch_bounds__(256, 8) void matern_mfma(const float* __restrict__ ls,
                                                      const float* __restrict__ x,
                                                      const bf8* __restrict__ ytbl,
                                                      const bf8* __restrict__ btbl,
                                                      float* __restrict__ out) {
    const int t = threadIdx.x;
    const int lane = t & 63, wave = t >> 6;
    const int n = lane & 15, quad = lane >> 4;
    const int waverow = blockIdx.x * ROWS_BLK + wave * ROWS_WAVE;

    // [wave][mt][m][40]: 80B rows, 16B-aligned reads; <=2-way conflicts (free)
    __shared__ __attribute__((aligned(16))) unsigned short klds[WAVES][MT][16][40];

    float lsv[DD];
#pragma unroll
    for (int d = 0; d < DD; ++d) lsv[d] = ls[d];

    // A-frags: quad 0/2 -> xls_hi, quad 1 -> xls_lo, quad 3 -> {1,1,sx_hi,sx_lo,0..}
    bf8 afrag[MT];
#pragma unroll
    for (int mt = 0; mt < MT; ++mt) {
        const float* xr = x + (size_t)(waverow + mt * 16 + n) * DD;
        float sx = 0.f;
        unsigned short xh[DD], xl[DD];
#pragma unroll
        for (int d = 0; d < DD; ++d) {
            float xv = xr[d];
            float xlsv = lsv[d] * xv;
            sx = fmaf(xlsv, xv, sx);
            xh[d] = f2bf(xlsv);
            xl[d] = f2bf(xlsv - bf2f(xh[d]));
        }
        bf8 fr;
        if (quad == 3) {
            unsigned short sh = f2bf(sx);
            unsigned short sl = f2bf(sx - bf2f(sh));
            fr[0] = BF16_ONE;   // k=24: 1 * sy_hi
            fr[1] = BF16_ONE;   // k=25: 1 * sy_lo
            fr[2] = (short)sh;  // k=26: sx_hi * 1
            fr[3] = (short)sl;  // k=27: sx_lo * 1
            fr[4] = 0; fr[5] = 0; fr[6] = 0; fr[7] = 0;
        } else {
#pragma unroll
            for (int d = 0; d < DD; ++d)
                fr[d] = (short)((quad == 1) ? xl[d] : xh[d]);
        }
        afrag[mt] = fr;
    }

    const float c3sq = 10.406922f;       // (sqrt(5)*log2(e))^2
    const float ln2  = 0.6931471805599453f;
    const float c2   = 1.2909944487358056f;  // sqrt(5/3)

    f32x4 acc[MT];
#pragma unroll
    for (int mt = 0; mt < MT; ++mt) acc[mt] = (f32x4){0.f, 0.f, 0.f, 0.f};

    const int tile16base = blockIdx.y * (JCHUNK / 16);
    const int tile32base = blockIdx.y * (JCHUNK / 32);

#pragma unroll 1
    for (int it = 0; it < J32; ++it) {
        const int tl0 = tile16base + it * 2;
        bf8 yA = ytbl[(size_t)tl0 * 64 + lane];
        bf8 yB = ytbl[(size_t)(tl0 + 1) * 64 + lane];
        bf8 bb = btbl[(size_t)(tile32base + it) * 64 + lane];

#pragma unroll
        for (int mt = 0; mt < MT; ++mt) {
            f32x4 z = (f32x4){0.f, 0.f, 0.f, 0.f};
            f32x4 s0 = __builtin_amdgcn_mfma_f32_16x16x32_bf16(afrag[mt], yA, z, 0, 0, 0);
            f32x4 s1 = __builtin_amdgcn_mfma_f32_16x16x32_bf16(afrag[mt], yB, z, 0, 0, 0);
#pragma unroll
            for (int s = 0; s < 4; ++s) {
                // s0/s1 ARE d2 (MFMA computed sx+sy-2*dot); |.| handles
                // rounding-noise negatives via free input modifiers.
                float a0 = __builtin_fabsf(s0[s]);
                float a1 = __builtin_fabsf(s1[s]);
                float t0 = __builtin_amdgcn_sqrtf(c3sq * a0);   // |c3| * r
                float t1 = __builtin_amdgcn_sqrtf(c3sq * a1);
                float e0 = __builtin_amdgcn_exp2f(-t0);         // neg = free mod
                float e1 = __builtin_amdgcn_exp2f(-t1);
                float k0 = fmaf(c2, a0, fmaf(ln2, t0, 1.f)) * e0;
                float k1 = fmaf(c2, a1, fmaf(ln2, t1, 1.f)) * e1;
#if __has_builtin(__builtin_amdgcn_cvt_pk_bf16_f32)
                typedef __bf16 bf2v __attribute__((ext_vector_type(2)));
                bf2v pk = __builtin_amdgcn_cvt_pk_bf16_f32(k0, k1);
                union { bf2v v; unsigned short u[2]; } cv; cv.v = pk;
                klds[wave][mt][quad * 4 + s][n] = cv.u[0];
                klds[wave][mt][quad * 4 + s][n + 16] = cv.u[1];
#else
                // round-half-up bf16 (k>0): proven 2-op path
                klds[wave][mt][quad * 4 + s][n] =
                    (unsigned short)((__float_as_uint(k0) + 0x8000u) >> 16);
                klds[wave][mt][quad * 4 + s][n + 16] =
                    (unsigned short)((__float_as_uint(k1) + 0x8000u) >> 16);
#endif
            }
        }
        // C/D->A layout: lane reads A'[m=lane&15][k=quad*8+s] as one 16B LDS read
#pragma unroll
        for (int mt = 0; mt < MT; ++mt) {
            const bf8* kp = (const bf8*)&klds[wave][mt][n][quad * 8];
            acc[mt] = __builtin_amdgcn_mfma_f32_16x16x32_bf16(*kp, bb, acc[mt], 0, 0, 0);
        }
    }

    // Epilogue: D layout row=quad*4+s, col=n; JSPLIT partial sums via atomics
#pragma unroll
    for (int mt = 0; mt < MT; ++mt)
#pragma unroll
        for (int s = 0; s < 4; ++s) {
            const int row = waverow + mt * 16 + quad * 4 + s;
            atomicAdd(out + (size_t)row * DV + n, acc[mt][s]);
        }
}

extern "C" void kernel_launch(void* const* d_in, const int* in_sizes, int n_in,
                              void* d_out, int out_size, void* d_ws, size_t ws_size,
                              hipStream_t stream) {
    const float* ls = (const float*)d_in[0];
    const float* x  = (const float*)d_in[1];
    const float* y  = (const float*)d_in[2];
    const float* b  = (const float*)d_in[3];
    float* out = (float*)d_out;

    char* ws = (char*)d_ws;
    bf8* ytbl = (bf8*)ws;                        // 1024*64*16B = 1 MB
    bf8* btbl = (bf8*)(ws + (1 << 20));          // 512*64*16B  = 512 KB

    prep_frags<<<MM / 64, 256, 0, stream>>>(ls, y, b, ytbl, btbl, (float4*)out);
    matern_mfma<<<dim3(NN / ROWS_BLK, JSPLIT), 256, 0, stream>>>(ls, x, ytbl, btbl, out);
}

// Round 14
// 135.362 us; speedup vs baseline: 1.2651x; 1.0204x over previous
//
#include <hip/hip_runtime.h>
#include <stdint.h>

#define NN 16384
#define MM 16384
#define DD 8
#define DV 16
#define WAVES 4
#define MT 2                        // 16-row m-tiles per wave
#define ROWS_WAVE (MT * 16)         // 32
#define ROWS_BLK (WAVES * ROWS_WAVE)// 128
#define JSPLIT 32
#define JCHUNK (MM / JSPLIT)        // 512
#define J32 (JCHUNK / 32)           // 16 iterations per block

typedef short bf8 __attribute__((ext_vector_type(8)));   // 8 bf16 (4 VGPR)
typedef short s2v __attribute__((ext_vector_type(2)));   // 2 bf16, one b32 store
typedef float f32x4 __attribute__((ext_vector_type(4))); // MFMA C/D

#define C3SQ 10.406844905028037f     /* 5*log2(e)^2 : folded into tables */
#define C2S  (1.2909944487358056f / 10.406844905028037f)  /* c2/c3sq */
#define LN2  0.6931471805599453f

__device__ __forceinline__ unsigned short f2bf(float f) {
    union { float f; uint32_t u; } c; c.f = f;
    uint32_t u = c.u + 0x7FFF + ((c.u >> 16) & 1);       // RNE
    return (unsigned short)(u >> 16);
}
__device__ __forceinline__ float bf2f(unsigned short h) {
    union { float f; uint32_t u; } c; c.u = ((uint32_t)h) << 16;
    return c.f;
}

#define BF16_ONE ((short)0x3F80)

// Tables with the SCALED d2 fold: MFMA emits z = c3sq*d2 directly.
//   quads 0..2 of B hold w = -2*c3sq*y (split hi,hi,lo AFTER fp32 scaling)
//   quad 3: A {1,1,csx_hi,csx_lo} x B {csy_hi,csy_lo,1,1}, c* = c3sq-scaled
// btbl K-order PERMUTED to match interleaved klds columns:
//   k -> j_local = (k>>1) + ((k&1)<<4)
__global__ __launch_bounds__(256) void prep_frags(const float* __restrict__ ls,
                                                  const float* __restrict__ y,
                                                  const float* __restrict__ b,
                                                  bf8* __restrict__ ytbl,
                                                  bf8* __restrict__ btbl,
                                                  float4* __restrict__ outz) {
    const int tile = blockIdx.x * 4 + (threadIdx.x >> 6);  // 0..1023 (j16 tiles)
    const int lane = threadIdx.x & 63;
    const int n = lane & 15, quad = lane >> 4;

    // zero d_out: 256 blocks * 256 threads * 16B = 1 MB
    outz[blockIdx.x * 256 + threadIdx.x] = make_float4(0.f, 0.f, 0.f, 0.f);

    float lsv[DD];
#pragma unroll
    for (int d = 0; d < DD; ++d) lsv[d] = ls[d];

    const float4* yr4 = (const float4*)(y + (size_t)(tile * 16 + n) * DD);
    float4 ya = yr4[0], yb = yr4[1];
    float yv[DD] = {ya.x, ya.y, ya.z, ya.w, yb.x, yb.y, yb.z, yb.w};

    float syv = 0.f;
    unsigned short wh[DD], wl[DD];
#pragma unroll
    for (int d = 0; d < DD; ++d) {
        syv = fmaf(lsv[d] * yv[d], yv[d], syv);
        float w = -2.f * C3SQ * yv[d];          // scale in fp32, THEN split
        wh[d] = f2bf(w);
        wl[d] = f2bf(w - bf2f(wh[d]));
    }

    bf8 fr;
    if (quad < 3) {
#pragma unroll
        for (int d = 0; d < DD; ++d)
            fr[d] = (short)((quad == 2) ? wl[d] : wh[d]);
    } else {
        float csy = C3SQ * syv;
        unsigned short sh = f2bf(csy);
        unsigned short sl = f2bf(csy - bf2f(sh));
        fr[0] = (short)sh;      // k=24: 1 * csy_hi
        fr[1] = (short)sl;      // k=25: 1 * csy_lo
        fr[2] = BF16_ONE;       // k=26: csx_hi * 1
        fr[3] = BF16_ONE;       // k=27: csx_lo * 1
        fr[4] = 0; fr[5] = 0; fr[6] = 0; fr[7] = 0;
    }
    ytbl[tile * 64 + lane] = fr;

    if (tile < MM / 32) {             // j32 tiles for phase B, PERMUTED K-order
        bf8 bfr;
#pragma unroll
        for (int s = 0; s < 8; ++s) {
            int k = quad * 8 + s;
            int jl = (k >> 1) + ((k & 1) << 4);   // interleaved klds col -> j
            float bv = b[(size_t)(tile * 32 + jl) * DV + n];
            bfr[s] = (short)f2bf(bv);
        }
        btbl[tile * 64 + lane] = bfr;
    }
}

// R12 structure (proven PASS, 138us) + issue-slot trims:
//  - c3sq folded into tables: MFMA emits z=c3sq*d2; transform loses the mul
//  - k-pair (tile0,tile1) packed to one b32 LDS write at interleaved cols
//    2n/2n+1 (btbl K-permuted to match); b32 writes are 2-way bank-free
//    (b16 writes were 4-way: the 2.1M SQ_LDS_BANK_CONFLICT)
//  - NO inline asm (R6-R8 culprit), short-vector stores (legal aliasing)
__global__ __launch_bounds__(256, 8) void matern_mfma(const float* __restrict__ ls,
                                                      const float* __restrict__ x,
                                                      const bf8* __restrict__ ytbl,
                                                      const bf8* __restrict__ btbl,
                                                      float* __restrict__ out) {
    const int t = threadIdx.x;
    const int lane = t & 63, wave = t >> 6;
    const int n = lane & 15, quad = lane >> 4;
    const int waverow = blockIdx.x * ROWS_BLK + wave * ROWS_WAVE;

    // [wave][mt][m][40]: 80B rows; b32 writes (20*row+n)%32 -> 2-way free;
    // b128 reads 16B-aligned, 2-way free (R5-proven).
    __shared__ __attribute__((aligned(16))) unsigned short klds[WAVES][MT][16][40];

    float lsv[DD];
#pragma unroll
    for (int d = 0; d < DD; ++d) lsv[d] = ls[d];

    // A-frags: quad 0/2 -> xls_hi, quad 1 -> xls_lo, quad 3 -> {1,1,csx_hi,csx_lo}
    bf8 afrag[MT];
#pragma unroll
    for (int mt = 0; mt < MT; ++mt) {
        const float* xr = x + (size_t)(waverow + mt * 16 + n) * DD;
        float sx = 0.f;
        unsigned short xh[DD], xl[DD];
#pragma unroll
        for (int d = 0; d < DD; ++d) {
            float xv = xr[d];
            float xlsv = lsv[d] * xv;
            sx = fmaf(xlsv, xv, sx);
            xh[d] = f2bf(xlsv);
            xl[d] = f2bf(xlsv - bf2f(xh[d]));
        }
        bf8 fr;
        if (quad == 3) {
            float csx = C3SQ * sx;               // scale in fp32, THEN split
            unsigned short sh = f2bf(csx);
            unsigned short sl = f2bf(csx - bf2f(sh));
            fr[0] = BF16_ONE;   // k=24: 1 * csy_hi
            fr[1] = BF16_ONE;   // k=25: 1 * csy_lo
            fr[2] = (short)sh;  // k=26: csx_hi * 1
            fr[3] = (short)sl;  // k=27: csx_lo * 1
            fr[4] = 0; fr[5] = 0; fr[6] = 0; fr[7] = 0;
        } else {
#pragma unroll
            for (int d = 0; d < DD; ++d)
                fr[d] = (short)((quad == 1) ? xl[d] : xh[d]);
        }
        afrag[mt] = fr;
    }

    f32x4 acc[MT];
#pragma unroll
    for (int mt = 0; mt < MT; ++mt) acc[mt] = (f32x4){0.f, 0.f, 0.f, 0.f};

    const int tile16base = blockIdx.y * (JCHUNK / 16);
    const int tile32base = blockIdx.y * (JCHUNK / 32);

#pragma unroll 1
    for (int it = 0; it < J32; ++it) {
        const int tl0 = tile16base + it * 2;
        bf8 yA = ytbl[(size_t)tl0 * 64 + lane];
        bf8 yB = ytbl[(size_t)(tl0 + 1) * 64 + lane];
        bf8 bb = btbl[(size_t)(tile32base + it) * 64 + lane];

#pragma unroll
        for (int mt = 0; mt < MT; ++mt) {
            f32x4 z = (f32x4){0.f, 0.f, 0.f, 0.f};
            f32x4 s0 = __builtin_amdgcn_mfma_f32_16x16x32_bf16(afrag[mt], yA, z, 0, 0, 0);
            f32x4 s1 = __builtin_amdgcn_mfma_f32_16x16x32_bf16(afrag[mt], yB, z, 0, 0, 0);
#pragma unroll
            for (int s = 0; s < 4; ++s) {
                // s0/s1 ARE c3sq*d2; |.| eats rounding-noise negatives (free mod)
                float a0 = __builtin_fabsf(s0[s]);
                float a1 = __builtin_fabsf(s1[s]);
                float t0 = __builtin_amdgcn_sqrtf(a0);          // = |c3|*r
                float t1 = __builtin_amdgcn_sqrtf(a1);
                float e0 = __builtin_amdgcn_exp2f(-t0);         // neg = free mod
                float e1 = __builtin_amdgcn_exp2f(-t1);
                float k0 = fmaf(C2S, a0, fmaf(LN2, t0, 1.f)) * e0;
                float k1 = fmaf(C2S, a1, fmaf(LN2, t1, 1.f)) * e1;
                s2v w;
#if __has_builtin(__builtin_amdgcn_cvt_pk_bf16_f32)
                typedef __bf16 bf2v __attribute__((ext_vector_type(2)));
                bf2v pk = __builtin_amdgcn_cvt_pk_bf16_f32(k0, k1);
                union { bf2v v; s2v s; } cv; cv.v = pk;
                w = cv.s;
#else
                // round-half-up bf16 (k>0): proven 2-op path per value
                w[0] = (short)((__float_as_uint(k0) + 0x8000u) >> 16);
                w[1] = (short)((__float_as_uint(k1) + 0x8000u) >> 16);
#endif
                // one b32 store: cols 2n (tile0) / 2n+1 (tile1), interleaved
                *(s2v*)&klds[wave][mt][quad * 4 + s][2 * n] = w;
            }
        }
        // C/D->A: lane reads A'[m=lane&15][k=quad*8+s] as one 16B LDS read;
        // interleaved cols match btbl's permuted K-order.
#pragma unroll
        for (int mt = 0; mt < MT; ++mt) {
            const bf8* kp = (const bf8*)&klds[wave][mt][n][quad * 8];
            acc[mt] = __builtin_amdgcn_mfma_f32_16x16x32_bf16(*kp, bb, acc[mt], 0, 0, 0);
        }
    }

    // Epilogue: D layout row=quad*4+s, col=n; JSPLIT partial sums via atomics
#pragma unroll
    for (int mt = 0; mt < MT; ++mt)
#pragma unroll
        for (int s = 0; s < 4; ++s) {
            const int row = waverow + mt * 16 + quad * 4 + s;
            atomicAdd(out + (size_t)row * DV + n, acc[mt][s]);
        }
}

extern "C" void kernel_launch(void* const* d_in, const int* in_sizes, int n_in,
                              void* d_out, int out_size, void* d_ws, size_t ws_size,
                              hipStream_t stream) {
    const float* ls = (const float*)d_in[0];
    const float* x  = (const float*)d_in[1];
    const float* y  = (const float*)d_in[2];
    const float* b  = (const float*)d_in[3];
    float* out = (float*)d_out;

    char* ws = (char*)d_ws;
    bf8* ytbl = (bf8*)ws;                        // 1024*64*16B = 1 MB
    bf8* btbl = (bf8*)(ws + (1 << 20));          // 512*64*16B  = 512 KB

    prep_frags<<<MM / 64, 256, 0, stream>>>(ls, y, b, ytbl, btbl, (float4*)out);
    matern_mfma<<<dim3(NN / ROWS_BLK, JSPLIT), 256, 0, stream>>>(ls, x, ytbl, btbl, out);
}